// Round 1
// baseline (233.640 us; speedup 1.0000x reference)
//
#include <hip/hip_runtime.h>
#include <hip/hip_bf16.h>
#include <math.h>

#define B_ 2
#define S_ 2048
#define D_ 1024
#define H_ 16
#define HD_ 64
#define M_ (B_*S_)          // 4096 rows
#define SCALE_ 0.125f       // HD^-0.5

typedef float f32x4 __attribute__((ext_vector_type(4)));
typedef short s16x8 __attribute__((ext_vector_type(8)));
typedef float f32x4v __attribute__((ext_vector_type(4)));

__device__ __forceinline__ short f2bf(float f) {
  union { float f; unsigned u; } x; x.f = f;
  unsigned r = x.u + 0x7fffu + ((x.u >> 16) & 1u);   // RNE
  return (short)(r >> 16);
}

// ---------------- fp32 -> bf16 convert (8 elems/thread) ----------------
__global__ __launch_bounds__(256) void k_cvt_bf16(const float* __restrict__ in,
                                                  short* __restrict__ out, int n) {
  int i = (blockIdx.x * 256 + threadIdx.x) * 8;
  if (i >= n) return;
  f32x4v a = *reinterpret_cast<const f32x4v*>(in + i);
  f32x4v b = *reinterpret_cast<const f32x4v*>(in + i + 4);
  s16x8 v;
  v[0]=f2bf(a[0]); v[1]=f2bf(a[1]); v[2]=f2bf(a[2]); v[3]=f2bf(a[3]);
  v[4]=f2bf(b[0]); v[5]=f2bf(b[1]); v[6]=f2bf(b[2]); v[7]=f2bf(b[3]);
  *reinterpret_cast<s16x8*>(out + i) = v;
}

// ---------------- W (DxD fp32, row-major KxN) -> Wt (NxK bf16) ----------------
__global__ __launch_bounds__(256) void k_transpose_cvt(const float* __restrict__ W,
                                                       short* __restrict__ Wt) {
  int gid = blockIdx.x * 256 + threadIdx.x;    // D*D/8 threads
  int n  = gid & (D_ - 1);
  int k0 = (gid >> 10) * 8;
  s16x8 v;
  #pragma unroll
  for (int i = 0; i < 8; ++i) v[i] = f2bf(W[(size_t)(k0 + i) * D_ + n]);
  *reinterpret_cast<s16x8*>(Wt + (size_t)n * D_ + k0) = v;
}

// ---------------- GEMM: C[MxN] = A[MxK] @ Bt[NxK]^T + bias ----------------
// bf16 in, fp32 acc. Tile 128x64, BK=64, 4 waves (2x2), XOR-swizzled LDS.
template <bool OUT_BF16>
__global__ __launch_bounds__(256) void k_gemm_bt(const short* __restrict__ A,
                                                 const short* __restrict__ Bt,
                                                 const float* __restrict__ bias,
                                                 void* __restrict__ C,
                                                 int M, int N, int K) {
  __shared__ char lA[128 * 128];   // 128 rows x 64 bf16 (128B rows), swizzled
  __shared__ char lB[64 * 128];    // 64 rows x 64 bf16
  const int t = threadIdx.x;
  const int lane = t & 63, wid = t >> 6;
  const int l15 = lane & 15, l4 = lane >> 4;
  const int wm = wid >> 1, wn = wid & 1;     // 2x2 wave grid
  const int m0 = blockIdx.x * 128, n0 = blockIdx.y * 64;

  f32x4 acc[4][2];
  #pragma unroll
  for (int i = 0; i < 4; ++i)
    #pragma unroll
    for (int j = 0; j < 2; ++j) acc[i][j] = (f32x4){0.f, 0.f, 0.f, 0.f};

  for (int k0 = 0; k0 < K; k0 += 64) {
    #pragma unroll
    for (int i = 0; i < 4; ++i) {          // A: 1024 16B-slots
      int slot = t + i * 256;
      int row = slot >> 3, s = slot & 7;
      s16x8 va = *reinterpret_cast<const s16x8*>(A + (size_t)(m0 + row) * K + k0 + s * 8);
      *reinterpret_cast<s16x8*>(lA + row * 128 + ((s ^ (row & 7)) * 16)) = va;
    }
    #pragma unroll
    for (int i = 0; i < 2; ++i) {          // B: 512 16B-slots
      int slot = t + i * 256;
      int row = slot >> 3, s = slot & 7;
      s16x8 vb = *reinterpret_cast<const s16x8*>(Bt + (size_t)(n0 + row) * K + k0 + s * 8);
      *reinterpret_cast<s16x8*>(lB + row * 128 + ((s ^ (row & 7)) * 16)) = vb;
    }
    __syncthreads();
    #pragma unroll
    for (int ks = 0; ks < 2; ++ks) {
      s16x8 af[4], bfr[2];
      #pragma unroll
      for (int mt = 0; mt < 4; ++mt) {
        int row = wm * 64 + mt * 16 + l15;
        af[mt] = *reinterpret_cast<const s16x8*>(lA + row * 128 + (((ks*4 + l4) ^ (row & 7)) * 16));
      }
      #pragma unroll
      for (int nt = 0; nt < 2; ++nt) {
        int row = wn * 32 + nt * 16 + l15;
        bfr[nt] = *reinterpret_cast<const s16x8*>(lB + row * 128 + (((ks*4 + l4) ^ (row & 7)) * 16));
      }
      #pragma unroll
      for (int mt = 0; mt < 4; ++mt)
        #pragma unroll
        for (int nt = 0; nt < 2; ++nt)
          acc[mt][nt] = __builtin_amdgcn_mfma_f32_16x16x32_bf16(af[mt], bfr[nt], acc[mt][nt], 0, 0, 0);
    }
    __syncthreads();
  }
  // epilogue: C/D layout col=lane&15, row=(lane>>4)*4+reg
  #pragma unroll
  for (int nt = 0; nt < 2; ++nt) {
    int col = n0 + wn * 32 + nt * 16 + l15;
    float bv = bias[col];
    #pragma unroll
    for (int mt = 0; mt < 4; ++mt) {
      #pragma unroll
      for (int r = 0; r < 4; ++r) {
        int row = m0 + wm * 64 + mt * 16 + l4 * 4 + r;
        float v = acc[mt][nt][r] + bv;
        if (OUT_BF16) reinterpret_cast<short*>(C)[(size_t)row * N + col] = f2bf(v);
        else          reinterpret_cast<float*>(C)[(size_t)row * N + col] = v;
      }
    }
  }
}

// ---------------- flash attention ----------------
// grid (B*H, S/128); block 256 = 4 waves; wave owns 32 q-rows; KVBLK=64.
__global__ __launch_bounds__(256) void k_attn(const short* __restrict__ Q,
                                              const short* __restrict__ K,
                                              const short* __restrict__ V,
                                              short* __restrict__ O) {
  __shared__ char lK[64 * 128];       // [kv][d]  swizzled
  __shared__ char lVt[64 * 128];      // [d][kv]  swizzled (transposed V)
  __shared__ char lP[4][32 * 128];    // per-wave P tile [32 q][64 kv], swizzled
  const int t = threadIdx.x;
  const int lane = t & 63, wid = t >> 6;
  const int l15 = lane & 15, l4 = lane >> 4;
  const int bh = blockIdx.x, b = bh >> 4, h = bh & 15;
  const int q0 = blockIdx.y * 128;
  const size_t base = (size_t)b * S_ * D_ + h * HD_;

  // hoist Q fragments (A-operand): lane holds Q[row=l15][k=l4*8+i]
  s16x8 qf[2][2];
  #pragma unroll
  for (int mt = 0; mt < 2; ++mt) {
    int row = q0 + wid * 32 + mt * 16 + l15;
    #pragma unroll
    for (int ks = 0; ks < 2; ++ks)
      qf[mt][ks] = *reinterpret_cast<const s16x8*>(Q + base + (size_t)row * D_ + ks * 32 + l4 * 8);
  }

  f32x4 o_acc[2][4];
  float m_run[2][4], l_run[2][4];
  #pragma unroll
  for (int mt = 0; mt < 2; ++mt) {
    #pragma unroll
    for (int nt = 0; nt < 4; ++nt) o_acc[mt][nt] = (f32x4){0.f, 0.f, 0.f, 0.f};
    #pragma unroll
    for (int r = 0; r < 4; ++r) { m_run[mt][r] = -INFINITY; l_run[mt][r] = 0.f; }
  }

  for (int kv0 = 0; kv0 < S_; kv0 += 64) {
    // stage K-tile row-major + V-tile transposed
    #pragma unroll
    for (int i = 0; i < 2; ++i) {
      int slot = t + i * 256;
      int row = slot >> 3, s = slot & 7;
      s16x8 vk = *reinterpret_cast<const s16x8*>(K + base + (size_t)(kv0 + row) * D_ + s * 8);
      *reinterpret_cast<s16x8*>(lK + row * 128 + ((s ^ (row & 7)) * 16)) = vk;
      s16x8 vv = *reinterpret_cast<const s16x8*>(V + base + (size_t)(kv0 + row) * D_ + s * 8);
      #pragma unroll
      for (int j = 0; j < 8; ++j) {
        int d = s * 8 + j;
        *reinterpret_cast<short*>(lVt + d * 128 + ((row * 2) ^ ((d & 7) << 4))) = vv[j];
      }
    }
    __syncthreads();

    // QK^T -> sc (fp32), C-layout: row=l4*4+r, col=nt*16+l15
    f32x4 sc[2][4];
    #pragma unroll
    for (int mt = 0; mt < 2; ++mt)
      #pragma unroll
      for (int nt = 0; nt < 4; ++nt) sc[mt][nt] = (f32x4){0.f, 0.f, 0.f, 0.f};
    #pragma unroll
    for (int ks = 0; ks < 2; ++ks) {
      s16x8 kf[4];
      #pragma unroll
      for (int nt = 0; nt < 4; ++nt) {
        int row = nt * 16 + l15;
        kf[nt] = *reinterpret_cast<const s16x8*>(lK + row * 128 + (((ks*4 + l4) ^ (row & 7)) * 16));
      }
      #pragma unroll
      for (int mt = 0; mt < 2; ++mt)
        #pragma unroll
        for (int nt = 0; nt < 4; ++nt)
          sc[mt][nt] = __builtin_amdgcn_mfma_f32_16x16x32_bf16(qf[mt][ks], kf[nt], sc[mt][nt], 0, 0, 0);
    }
    #pragma unroll
    for (int mt = 0; mt < 2; ++mt)
      #pragma unroll
      for (int nt = 0; nt < 4; ++nt) sc[mt][nt] *= SCALE_;

    // online softmax; each 16-lane group owns rows l4*4+r
    float alpha[2][4];
    #pragma unroll
    for (int mt = 0; mt < 2; ++mt) {
      #pragma unroll
      for (int r = 0; r < 4; ++r) {
        float mx = fmaxf(fmaxf(sc[mt][0][r], sc[mt][1][r]), fmaxf(sc[mt][2][r], sc[mt][3][r]));
        #pragma unroll
        for (int d = 1; d < 16; d <<= 1) mx = fmaxf(mx, __shfl_xor(mx, d));
        float mnew = fmaxf(m_run[mt][r], mx);
        float a = __expf(m_run[mt][r] - mnew);
        m_run[mt][r] = mnew;
        alpha[mt][r] = a;
        float rs = 0.f;
        #pragma unroll
        for (int nt = 0; nt < 4; ++nt) {
          float p = __expf(sc[mt][nt][r] - mnew);
          sc[mt][nt][r] = p;
          rs += p;
        }
        #pragma unroll
        for (int d = 1; d < 16; d <<= 1) rs += __shfl_xor(rs, d);
        l_run[mt][r] = l_run[mt][r] * a + rs;
      }
    }

    // P -> per-wave LDS (bf16), rescale O
    #pragma unroll
    for (int mt = 0; mt < 2; ++mt) {
      #pragma unroll
      for (int nt = 0; nt < 4; ++nt) {
        #pragma unroll
        for (int r = 0; r < 4; ++r) {
          int row = mt * 16 + l4 * 4 + r;
          int col = nt * 16 + l15;
          *reinterpret_cast<short*>(lP[wid] + row * 128 + ((col * 2) ^ ((row & 7) << 4))) =
              f2bf(sc[mt][nt][r]);
        }
        #pragma unroll
        for (int r = 0; r < 4; ++r) o_acc[mt][nt][r] *= alpha[mt][r];
      }
    }

    // PV: A=P (q x kv), B=V (kv x d) read from transposed lVt
    #pragma unroll
    for (int ks = 0; ks < 2; ++ks) {
      s16x8 pf[2], vf[4];
      #pragma unroll
      for (int mt = 0; mt < 2; ++mt) {
        int row = mt * 16 + l15;
        pf[mt] = *reinterpret_cast<const s16x8*>(lP[wid] + row * 128 + (((ks*4 + l4) ^ (row & 7)) * 16));
      }
      #pragma unroll
      for (int nt = 0; nt < 4; ++nt) {
        int row = nt * 16 + l15;
        vf[nt] = *reinterpret_cast<const s16x8*>(lVt + row * 128 + (((ks*4 + l4) ^ (row & 7)) * 16));
      }
      #pragma unroll
      for (int mt = 0; mt < 2; ++mt)
        #pragma unroll
        for (int nt = 0; nt < 4; ++nt)
          o_acc[mt][nt] = __builtin_amdgcn_mfma_f32_16x16x32_bf16(pf[mt], vf[nt], o_acc[mt][nt], 0, 0, 0);
    }
    __syncthreads();
  }

  // epilogue: O /= l, write bf16 (B*S, D) layout
  #pragma unroll
  for (int mt = 0; mt < 2; ++mt)
    #pragma unroll
    for (int nt = 0; nt < 4; ++nt)
      #pragma unroll
      for (int r = 0; r < 4; ++r) {
        int row = q0 + wid * 32 + mt * 16 + l4 * 4 + r;
        int col = nt * 16 + l15;
        float v = o_acc[mt][nt][r] / l_run[mt][r];
        O[base + (size_t)row * D_ + col] = f2bf(v);
      }
}

extern "C" void kernel_launch(void* const* d_in, const int* in_sizes, int n_in,
                              void* d_out, int out_size, void* d_ws, size_t ws_size,
                              hipStream_t stream) {
  const float* query = (const float*)d_in[0];
  const float* Wq = (const float*)d_in[1];
  const float* bq = (const float*)d_in[2];
  const float* Wk = (const float*)d_in[3];
  const float* bk = (const float*)d_in[4];
  const float* Wv = (const float*)d_in[5];
  const float* bv = (const float*)d_in[6];
  const float* Wo = (const float*)d_in[7];
  const float* bo = (const float*)d_in[8];
  float* out = (float*)d_out;

  const size_t NE = (size_t)M_ * D_;           // 4,194,304 elems
  short* ws   = (short*)d_ws;                  // needs ~50.3 MB of ws
  short* xbf  = ws;                            // query bf16
  short* qbf  = ws + NE;
  short* kbf  = ws + 2 * NE;
  short* vbf  = ws + 3 * NE;
  short* aout = ws + 4 * NE;                   // attention output bf16
  short* wtq  = ws + 5 * NE;                   // 4x transposed bf16 weights
  short* wtk  = wtq + (size_t)D_ * D_;
  short* wtv  = wtk + (size_t)D_ * D_;
  short* wto  = wtv + (size_t)D_ * D_;

  k_cvt_bf16<<<(int)(NE / (8 * 256)), 256, 0, stream>>>(query, xbf, (int)NE);
  const int tgrid = (D_ * D_ / 8) / 256;       // 512
  k_transpose_cvt<<<tgrid, 256, 0, stream>>>(Wq, wtq);
  k_transpose_cvt<<<tgrid, 256, 0, stream>>>(Wk, wtk);
  k_transpose_cvt<<<tgrid, 256, 0, stream>>>(Wv, wtv);
  k_transpose_cvt<<<tgrid, 256, 0, stream>>>(Wo, wto);

  dim3 gg(M_ / 128, D_ / 64);                  // (32,16) = 512 blocks
  k_gemm_bt<true><<<gg, 256, 0, stream>>>(xbf, wtq, bq, qbf, M_, D_, D_);
  k_gemm_bt<true><<<gg, 256, 0, stream>>>(xbf, wtk, bk, kbf, M_, D_, D_);
  k_gemm_bt<true><<<gg, 256, 0, stream>>>(xbf, wtv, bv, vbf, M_, D_, D_);

  k_attn<<<dim3(B_ * H_, S_ / 128), 256, 0, stream>>>(qbf, kbf, vbf, aout);

  k_gemm_bt<false><<<gg, 256, 0, stream>>>(aout, wto, bo, out, M_, D_, D_);
}

// Round 2
// 178.371 us; speedup vs baseline: 1.3099x; 1.3099x over previous
//
#include <hip/hip_runtime.h>
#include <hip/hip_bf16.h>
#include <math.h>

#define B_ 2
#define S_ 2048
#define D_ 1024
#define H_ 16
#define HD_ 64
#define M_ (B_*S_)          // 4096 rows
#define SCALE_ 0.125f       // HD^-0.5
#define C1_ 0.1803368798f   // SCALE * log2(e)

typedef float f32x4 __attribute__((ext_vector_type(4)));
typedef short s16x8 __attribute__((ext_vector_type(8)));
typedef short s16x4 __attribute__((ext_vector_type(4)));

__device__ __forceinline__ short f2bf(float f) {
  union { float f; unsigned u; } x; x.f = f;
  unsigned r = x.u + 0x7fffu + ((x.u >> 16) & 1u);   // RNE
  return (short)(r >> 16);
}
__device__ __forceinline__ unsigned pack2(float a, float b) {
  return (unsigned)(unsigned short)f2bf(a) | ((unsigned)(unsigned short)f2bf(b) << 16);
}

// async global->LDS, 16B per lane; LDS dest = wave-uniform base + lane*16
__device__ __forceinline__ void gload_lds16(const void* g, void* l) {
  __builtin_amdgcn_global_load_lds(
      (const __attribute__((address_space(1))) void*)g,
      (__attribute__((address_space(3))) void*)l, 16, 0, 0);
}

// ---------------- fp32 -> bf16 convert (8 elems/thread) ----------------
__global__ __launch_bounds__(256) void k_cvt_bf16(const float* __restrict__ in,
                                                  short* __restrict__ out, int n) {
  int i = (blockIdx.x * 256 + threadIdx.x) * 8;
  if (i >= n) return;
  f32x4 a = *reinterpret_cast<const f32x4*>(in + i);
  f32x4 b = *reinterpret_cast<const f32x4*>(in + i + 4);
  s16x8 v;
  v[0]=f2bf(a[0]); v[1]=f2bf(a[1]); v[2]=f2bf(a[2]); v[3]=f2bf(a[3]);
  v[4]=f2bf(b[0]); v[5]=f2bf(b[1]); v[6]=f2bf(b[2]); v[7]=f2bf(b[3]);
  *reinterpret_cast<s16x8*>(out + i) = v;
}

// ---------------- W (DxD fp32, row-major KxN) -> Wt (NxK bf16) ----------------
__global__ __launch_bounds__(256) void k_transpose_cvt(const float* __restrict__ W,
                                                       short* __restrict__ Wt) {
  int gid = blockIdx.x * 256 + threadIdx.x;    // D*D/8 threads
  int n  = gid & (D_ - 1);
  int k0 = (gid >> 10) * 8;
  s16x8 v;
  #pragma unroll
  for (int i = 0; i < 8; ++i) v[i] = f2bf(W[(size_t)(k0 + i) * D_ + n]);
  *reinterpret_cast<s16x8*>(Wt + (size_t)n * D_ + k0) = v;
}

// ---------------- GEMM: C[MxN] = A[MxK] @ Bt[NxK]^T + bias ----------------
// OM: 0 = fp32 out, 1 = bf16 out, 2 = bf16 TRANSPOSED out (C[n][m])
template <int OM>
__global__ __launch_bounds__(256) void k_gemm_bt(const short* __restrict__ A,
                                                 const short* __restrict__ Bt,
                                                 const float* __restrict__ bias,
                                                 void* __restrict__ C,
                                                 int M, int N, int K) {
  __shared__ __align__(16) char lA[128 * 128];   // 128 rows x 64 bf16, swizzled content
  __shared__ __align__(16) char lB[64 * 128];
  const int t = threadIdx.x;
  const int lane = t & 63, wid = t >> 6;
  const int l15 = lane & 15, l4 = lane >> 4;
  const int wm = wid >> 1, wn = wid & 1;     // 2x2 wave grid
  const int m0 = blockIdx.x * 128, n0 = blockIdx.y * 64;

  f32x4 acc[4][2];
  #pragma unroll
  for (int i = 0; i < 4; ++i)
    #pragma unroll
    for (int j = 0; j < 2; ++j) acc[i][j] = (f32x4){0.f, 0.f, 0.f, 0.f};

  for (int k0 = 0; k0 < K; k0 += 64) {
    // stage via global_load_lds: LINEAR LDS dest + pre-swizzled global source
    #pragma unroll
    for (int i = 0; i < 4; ++i) {          // A: 1024 16B-slots
      int slot = t + i * 256;
      int row = slot >> 3, s = slot & 7;
      int sw = s ^ (row & 7);
      gload_lds16(A + (size_t)(m0 + row) * K + k0 + sw * 8,
                  lA + (i * 256 + wid * 64) * 16);
    }
    #pragma unroll
    for (int i = 0; i < 2; ++i) {          // B: 512 16B-slots
      int slot = t + i * 256;
      int row = slot >> 3, s = slot & 7;
      int sw = s ^ (row & 7);
      gload_lds16(Bt + (size_t)(n0 + row) * K + k0 + sw * 8,
                  lB + (i * 256 + wid * 64) * 16);
    }
    __syncthreads();
    #pragma unroll
    for (int ks = 0; ks < 2; ++ks) {
      s16x8 af[4], bfr[2];
      #pragma unroll
      for (int mt = 0; mt < 4; ++mt) {
        int row = wm * 64 + mt * 16 + l15;
        af[mt] = *reinterpret_cast<const s16x8*>(lA + row * 128 + (((ks*4 + l4) ^ (row & 7)) * 16));
      }
      #pragma unroll
      for (int nt = 0; nt < 2; ++nt) {
        int row = wn * 32 + nt * 16 + l15;
        bfr[nt] = *reinterpret_cast<const s16x8*>(lB + row * 128 + (((ks*4 + l4) ^ (row & 7)) * 16));
      }
      #pragma unroll
      for (int mt = 0; mt < 4; ++mt)
        #pragma unroll
        for (int nt = 0; nt < 2; ++nt)
          acc[mt][nt] = __builtin_amdgcn_mfma_f32_16x16x32_bf16(af[mt], bfr[nt], acc[mt][nt], 0, 0, 0);
    }
    __syncthreads();
  }
  // epilogue: C/D layout col=lane&15, row=(lane>>4)*4+reg
  #pragma unroll
  for (int nt = 0; nt < 2; ++nt) {
    int col = n0 + wn * 32 + nt * 16 + l15;
    float bv = bias[col];
    #pragma unroll
    for (int mt = 0; mt < 4; ++mt) {
      int row0 = m0 + wm * 64 + mt * 16 + l4 * 4;
      if (OM == 2) {
        s16x4 v4;
        #pragma unroll
        for (int r = 0; r < 4; ++r) v4[r] = f2bf(acc[mt][nt][r] + bv);
        *reinterpret_cast<s16x4*>(reinterpret_cast<short*>(C) + (size_t)col * M + row0) = v4;
      } else {
        #pragma unroll
        for (int r = 0; r < 4; ++r) {
          float v = acc[mt][nt][r] + bv;
          if (OM == 1) reinterpret_cast<short*>(C)[(size_t)(row0 + r) * N + col] = f2bf(v);
          else         reinterpret_cast<float*>(C)[(size_t)(row0 + r) * N + col] = v;
        }
      }
    }
  }
}

// ---------------- flash attention, swapped-QK^T, 8 waves ----------------
// grid (B*H, S/128); block 512 = 8 waves; wave owns 16 q-rows; KVBLK=64.
// V is stored TRANSPOSED in global: Vt[d=0..1023][m=0..4095].
__global__ __launch_bounds__(512, 4) void k_attn(const short* __restrict__ Q,
                                                 const short* __restrict__ K,
                                                 const short* __restrict__ Vt,
                                                 short* __restrict__ O) {
  __shared__ __align__(16) char lK[64 * 128];   // [kv][d] swizzled
  __shared__ __align__(16) char lV[64 * 128];   // [d][kv] swizzled
  const int t = threadIdx.x;
  const int lane = t & 63, wid = t >> 6;
  const int l15 = lane & 15, l4 = lane >> 4;
  const int bh = blockIdx.x, b = bh >> 4, h = bh & 15;
  const int q0 = blockIdx.y * 128;
  const size_t qkbase = (size_t)b * S_ * D_ + h * HD_;
  const short* gVt = Vt + (size_t)(h * HD_) * M_ + (size_t)b * S_;

  // Q fragments (B-operand of swapped QK^T): lane holds Q[q=l15][d=ks*32+l4*8+i]
  s16x8 qf[2];
  {
    const short* qp = Q + qkbase + (size_t)(q0 + wid * 16 + l15) * D_;
    qf[0] = *reinterpret_cast<const s16x8*>(qp + l4 * 8);
    qf[1] = *reinterpret_cast<const s16x8*>(qp + 32 + l4 * 8);
  }

  f32x4 o_acc[4];                  // O[q=l4*4+r][d=nt*16+l15]
  #pragma unroll
  for (int nt = 0; nt < 4; ++nt) o_acc[nt] = (f32x4){0.f, 0.f, 0.f, 0.f};
  float m_run = -INFINITY, l_run = 0.f;   // for q = l15

  const int srow = t >> 3, ss = t & 7;    // 512 threads -> 64 rows x 8 slots
  const int ssw = ss ^ (srow & 7);        // pre-swizzled source slot
  const short* gK = K + qkbase;
  char* lKw = lK + wid * 1024;            // wave-uniform LDS bases
  char* lVw = lV + wid * 1024;

  for (int kv0 = 0; kv0 < S_; kv0 += 64) {
    __syncthreads();                      // prev tile fully consumed
    gload_lds16(gK + (size_t)(kv0 + srow) * D_ + ssw * 8, lKw);
    gload_lds16(gVt + (size_t)srow * M_ + kv0 + ssw * 8, lVw);
    __syncthreads();                      // staging landed (vmcnt drained)

    // S^T = K·Q^T : lane holds S[q=l15][kv=kt*16+l4*4+r]
    f32x4 sc[4];
    #pragma unroll
    for (int kt = 0; kt < 4; ++kt) sc[kt] = (f32x4){0.f, 0.f, 0.f, 0.f};
    __builtin_amdgcn_s_setprio(1);
    #pragma unroll
    for (int ks = 0; ks < 2; ++ks) {
      #pragma unroll
      for (int kt = 0; kt < 4; ++kt) {
        int row = kt * 16 + l15;
        s16x8 kf = *reinterpret_cast<const s16x8*>(lK + row * 128 + (((ks*4 + l4) ^ (row & 7)) * 16));
        sc[kt] = __builtin_amdgcn_mfma_f32_16x16x32_bf16(kf, qf[ks], sc[kt], 0, 0, 0);
      }
    }
    __builtin_amdgcn_s_setprio(0);

    // in-register online softmax (one q per lane), scale folded into exp2
    float mx = sc[0][0];
    #pragma unroll
    for (int kt = 0; kt < 4; ++kt)
      #pragma unroll
      for (int r = 0; r < 4; ++r) mx = fmaxf(mx, sc[kt][r]);
    mx = fmaxf(mx, __shfl_xor(mx, 16));
    mx = fmaxf(mx, __shfl_xor(mx, 32));
    float mnew = fmaxf(m_run, mx);
    float alpha = exp2f((m_run - mnew) * C1_);
    float rs = 0.f;
    #pragma unroll
    for (int kt = 0; kt < 4; ++kt)
      #pragma unroll
      for (int r = 0; r < 4; ++r) {
        float p = exp2f((sc[kt][r] - mnew) * C1_);
        sc[kt][r] = p;
        rs += p;
      }
    rs += __shfl_xor(rs, 16);
    rs += __shfl_xor(rs, 32);
    l_run = l_run * alpha + rs;
    m_run = mnew;

    // pack P to bf16 pairs
    unsigned pk[4][2];
    #pragma unroll
    for (int kt = 0; kt < 4; ++kt) {
      pk[kt][0] = pack2(sc[kt][0], sc[kt][1]);
      pk[kt][1] = pack2(sc[kt][2], sc[kt][3]);
    }

    // rescale O by alpha (alpha lives at lane l15=q; O rows are q=l4*4+r)
    float ar[4];
    #pragma unroll
    for (int r = 0; r < 4; ++r) ar[r] = __shfl(alpha, l4 * 4 + r);
    #pragma unroll
    for (int nt = 0; nt < 4; ++nt)
      #pragma unroll
      for (int r = 0; r < 4; ++r) o_acc[nt][r] *= ar[r];

    // cross-lane exchange: build PV A-fragment A[q=l15][kv=ks*32+l4*8+i]
    const int sA = 32 * (l4 & 1) + l15;
    const int sB = sA + 16;
    const int hi = l4 >> 1;
    #pragma unroll
    for (int ks = 0; ks < 2; ++ks) {
      unsigned a0 = __shfl(pk[2*ks][0], sA),   a1 = __shfl(pk[2*ks][1], sA);
      unsigned b0 = __shfl(pk[2*ks+1][0], sA), b1 = __shfl(pk[2*ks+1][1], sA);
      unsigned c0 = __shfl(pk[2*ks][0], sB),   c1 = __shfl(pk[2*ks][1], sB);
      unsigned d0 = __shfl(pk[2*ks+1][0], sB), d1 = __shfl(pk[2*ks+1][1], sB);
      union { unsigned u[4]; s16x8 v; } pw;
      pw.u[0] = hi ? b0 : a0;
      pw.u[1] = hi ? b1 : a1;
      pw.u[2] = hi ? d0 : c0;
      pw.u[3] = hi ? d1 : c1;
      s16x8 pf = pw.v;
      __builtin_amdgcn_s_setprio(1);
      #pragma unroll
      for (int nt = 0; nt < 4; ++nt) {
        int row = nt * 16 + l15;
        s16x8 vf = *reinterpret_cast<const s16x8*>(lV + row * 128 + (((ks*4 + l4) ^ (row & 7)) * 16));
        o_acc[nt] = __builtin_amdgcn_mfma_f32_16x16x32_bf16(pf, vf, o_acc[nt], 0, 0, 0);
      }
      __builtin_amdgcn_s_setprio(0);
    }
  }

  // epilogue: O /= l, write bf16
  float lr[4];
  #pragma unroll
  for (int r = 0; r < 4; ++r) lr[r] = 1.f / __shfl(l_run, l4 * 4 + r);
  #pragma unroll
  for (int nt = 0; nt < 4; ++nt) {
    int col = nt * 16 + l15;
    #pragma unroll
    for (int r = 0; r < 4; ++r) {
      int row = q0 + wid * 16 + l4 * 4 + r;
      O[qkbase + (size_t)row * D_ + col] = f2bf(o_acc[nt][r] * lr[r]);
    }
  }
}

extern "C" void kernel_launch(void* const* d_in, const int* in_sizes, int n_in,
                              void* d_out, int out_size, void* d_ws, size_t ws_size,
                              hipStream_t stream) {
  const float* query = (const float*)d_in[0];
  const float* Wq = (const float*)d_in[1];
  const float* bq = (const float*)d_in[2];
  const float* Wk = (const float*)d_in[3];
  const float* bk = (const float*)d_in[4];
  const float* Wv = (const float*)d_in[5];
  const float* bv = (const float*)d_in[6];
  const float* Wo = (const float*)d_in[7];
  const float* bo = (const float*)d_in[8];
  float* out = (float*)d_out;

  const size_t NE = (size_t)M_ * D_;           // 4,194,304 elems
  short* ws   = (short*)d_ws;
  short* xbf  = ws;                            // query bf16
  short* qbf  = ws + NE;
  short* kbf  = ws + 2 * NE;
  short* vtbf = ws + 3 * NE;                   // V TRANSPOSED [D][M] bf16
  short* aout = ws + 4 * NE;                   // attention output bf16
  short* wtq  = ws + 5 * NE;                   // 4x transposed bf16 weights
  short* wtk  = wtq + (size_t)D_ * D_;
  short* wtv  = wtk + (size_t)D_ * D_;
  short* wto  = wtv + (size_t)D_ * D_;

  k_cvt_bf16<<<(int)(NE / (8 * 256)), 256, 0, stream>>>(query, xbf, (int)NE);
  const int tgrid = (D_ * D_ / 8) / 256;       // 512
  k_transpose_cvt<<<tgrid, 256, 0, stream>>>(Wq, wtq);
  k_transpose_cvt<<<tgrid, 256, 0, stream>>>(Wk, wtk);
  k_transpose_cvt<<<tgrid, 256, 0, stream>>>(Wv, wtv);
  k_transpose_cvt<<<tgrid, 256, 0, stream>>>(Wo, wto);

  dim3 gg(M_ / 128, D_ / 64);                  // (32,16) = 512 blocks
  k_gemm_bt<1><<<gg, 256, 0, stream>>>(xbf, wtq, bq, qbf, M_, D_, D_);
  k_gemm_bt<1><<<gg, 256, 0, stream>>>(xbf, wtk, bk, kbf, M_, D_, D_);
  k_gemm_bt<2><<<gg, 256, 0, stream>>>(xbf, wtv, bv, vtbf, M_, D_, D_);

  k_attn<<<dim3(B_ * H_, S_ / 128), 512, 0, stream>>>(qbf, kbf, vtbf, aout);

  k_gemm_bt<0><<<gg, 256, 0, stream>>>(aout, wto, bo, out, M_, D_, D_);
}

// Round 3
// 144.680 us; speedup vs baseline: 1.6149x; 1.2329x over previous
//
#include <hip/hip_runtime.h>
#include <hip/hip_bf16.h>
#include <math.h>

#define B_ 2
#define S_ 2048
#define D_ 1024
#define H_ 16
#define HD_ 64
#define M_ (B_*S_)          // 4096 rows
#define C1_ 0.1803368798f   // HD^-0.5 * log2(e)
#define THR_ 11.5f          // defer-max threshold (log2 units ~ e^8)

typedef float f32x4 __attribute__((ext_vector_type(4)));
typedef short s16x8 __attribute__((ext_vector_type(8)));
typedef short s16x4 __attribute__((ext_vector_type(4)));

__device__ __forceinline__ short f2bf(float f) {
  union { float f; unsigned u; } x; x.f = f;
  unsigned r = x.u + 0x7fffu + ((x.u >> 16) & 1u);   // RNE
  return (short)(r >> 16);
}
__device__ __forceinline__ unsigned cvt_pk_bf16(float a, float b) {
  unsigned r;
  asm("v_cvt_pk_bf16_f32 %0, %1, %2" : "=v"(r) : "v"(a), "v"(b));
  return r;
}

// async global->LDS, 16B per lane; LDS dest = wave-uniform base + lane*16
__device__ __forceinline__ void gload_lds16(const void* g, void* l) {
  __builtin_amdgcn_global_load_lds(
      (const __attribute__((address_space(1))) void*)g,
      (__attribute__((address_space(3))) void*)l, 16, 0, 0);
}

// ---------------- fp32 -> bf16 convert (8 elems/thread) ----------------
__global__ __launch_bounds__(256) void k_cvt_bf16(const float* __restrict__ in,
                                                  short* __restrict__ out, int n) {
  int i = (blockIdx.x * 256 + threadIdx.x) * 8;
  if (i >= n) return;
  f32x4 a = *reinterpret_cast<const f32x4*>(in + i);
  f32x4 b = *reinterpret_cast<const f32x4*>(in + i + 4);
  s16x8 v;
  v[0]=f2bf(a[0]); v[1]=f2bf(a[1]); v[2]=f2bf(a[2]); v[3]=f2bf(a[3]);
  v[4]=f2bf(b[0]); v[5]=f2bf(b[1]); v[6]=f2bf(b[2]); v[7]=f2bf(b[3]);
  *reinterpret_cast<s16x8*>(out + i) = v;
}

// ---------------- 4x W (DxD fp32, KxN) -> Wt (NxK bf16), fused ----------------
__global__ __launch_bounds__(256) void k_transpose4(
    const float* __restrict__ W0, const float* __restrict__ W1,
    const float* __restrict__ W2, const float* __restrict__ W3,
    short* __restrict__ T0, short* __restrict__ T1,
    short* __restrict__ T2, short* __restrict__ T3) {
  int z = blockIdx.y;
  const float* W = z == 0 ? W0 : z == 1 ? W1 : z == 2 ? W2 : W3;
  short* Wt      = z == 0 ? T0 : z == 1 ? T1 : z == 2 ? T2 : T3;
  int gid = blockIdx.x * 256 + threadIdx.x;    // D*D/8 threads
  int n  = gid & (D_ - 1);
  int k0 = (gid >> 10) * 8;
  s16x8 v;
  #pragma unroll
  for (int i = 0; i < 8; ++i) v[i] = f2bf(W[(size_t)(k0 + i) * D_ + n]);
  *reinterpret_cast<s16x8*>(Wt + (size_t)n * D_ + k0) = v;
}

// ---------------- fused QKV GEMM: 128x128 tile, m97 structure ----------------
// z=0: Q (bf16 out, pre-scaled by C1_), z=1: K (bf16), z=2: V (bf16 TRANSPOSED out)
__global__ __launch_bounds__(256) void k_gemm_qkv(
    const short* __restrict__ A,
    const short* __restrict__ WtQ, const short* __restrict__ WtK, const short* __restrict__ WtV,
    const float* __restrict__ bQ, const float* __restrict__ bK, const float* __restrict__ bV,
    short* __restrict__ Qo, short* __restrict__ Ko, short* __restrict__ Vto) {
  __shared__ __align__(16) char lA[128 * 128];
  __shared__ __align__(16) char lB[128 * 128];
  const int z = blockIdx.z;
  const short* Bt   = z == 0 ? WtQ : z == 1 ? WtK : WtV;
  const float* bias = z == 0 ? bQ  : z == 1 ? bK  : bV;
  const int t = threadIdx.x;
  const int lane = t & 63, wid = t >> 6;
  const int l15 = lane & 15, l4 = lane >> 4;
  const int wm = wid >> 1, wn = wid & 1;
  const int m0 = blockIdx.x * 128, n0 = blockIdx.y * 128;

  f32x4 acc[4][4];
  #pragma unroll
  for (int i = 0; i < 4; ++i)
    #pragma unroll
    for (int j = 0; j < 4; ++j) acc[i][j] = (f32x4){0.f, 0.f, 0.f, 0.f};

  for (int k0 = 0; k0 < D_; k0 += 64) {
    #pragma unroll
    for (int i = 0; i < 4; ++i) {
      int slot = t + i * 256;
      int row = slot >> 3, sw = (t & 7) ^ (row & 7);
      gload_lds16(A  + (size_t)(m0 + row) * D_ + k0 + sw * 8, lA + (i * 256 + wid * 64) * 16);
      gload_lds16(Bt + (size_t)(n0 + row) * D_ + k0 + sw * 8, lB + (i * 256 + wid * 64) * 16);
    }
    __syncthreads();
    #pragma unroll
    for (int ks = 0; ks < 2; ++ks) {
      s16x8 af[4], bf[4];
      #pragma unroll
      for (int mt = 0; mt < 4; ++mt) {
        int row = wm * 64 + mt * 16 + l15;
        af[mt] = *reinterpret_cast<const s16x8*>(lA + row * 128 + (((ks*4 + l4) ^ (row & 7)) * 16));
      }
      #pragma unroll
      for (int nt = 0; nt < 4; ++nt) {
        int row = wn * 64 + nt * 16 + l15;
        bf[nt] = *reinterpret_cast<const s16x8*>(lB + row * 128 + (((ks*4 + l4) ^ (row & 7)) * 16));
      }
      #pragma unroll
      for (int mt = 0; mt < 4; ++mt)
        #pragma unroll
        for (int nt = 0; nt < 4; ++nt)
          acc[mt][nt] = __builtin_amdgcn_mfma_f32_16x16x32_bf16(af[mt], bf[nt], acc[mt][nt], 0, 0, 0);
    }
    __syncthreads();
  }

  const float scale = (z == 0) ? C1_ : 1.f;
  #pragma unroll
  for (int nt = 0; nt < 4; ++nt) {
    int col = n0 + wn * 64 + nt * 16 + l15;
    float bv = bias[col];
    #pragma unroll
    for (int mt = 0; mt < 4; ++mt) {
      int row0 = m0 + wm * 64 + mt * 16 + l4 * 4;
      if (z == 2) {
        s16x4 v4;
        #pragma unroll
        for (int r = 0; r < 4; ++r) v4[r] = f2bf(acc[mt][nt][r] + bv);
        *reinterpret_cast<s16x4*>(Vto + (size_t)col * M_ + row0) = v4;
      } else {
        short* out = (z == 0) ? Qo : Ko;
        #pragma unroll
        for (int r = 0; r < 4; ++r)
          out[(size_t)(row0 + r) * D_ + col] = f2bf((acc[mt][nt][r] + bv) * scale);
      }
    }
  }
}

// ---------------- Wo GEMM: C[MxN] fp32 = A @ Bt^T + bias (128x64 tile) ----------------
__global__ __launch_bounds__(256) void k_gemm_out(const short* __restrict__ A,
                                                  const short* __restrict__ Bt,
                                                  const float* __restrict__ bias,
                                                  float* __restrict__ C) {
  __shared__ __align__(16) char lA[128 * 128];
  __shared__ __align__(16) char lB[64 * 128];
  const int t = threadIdx.x;
  const int lane = t & 63, wid = t >> 6;
  const int l15 = lane & 15, l4 = lane >> 4;
  const int wm = wid >> 1, wn = wid & 1;
  const int m0 = blockIdx.x * 128, n0 = blockIdx.y * 64;

  f32x4 acc[4][2];
  #pragma unroll
  for (int i = 0; i < 4; ++i)
    #pragma unroll
    for (int j = 0; j < 2; ++j) acc[i][j] = (f32x4){0.f, 0.f, 0.f, 0.f};

  for (int k0 = 0; k0 < D_; k0 += 64) {
    #pragma unroll
    for (int i = 0; i < 4; ++i) {
      int slot = t + i * 256;
      int row = slot >> 3, sw = (t & 7) ^ (row & 7);
      gload_lds16(A + (size_t)(m0 + row) * D_ + k0 + sw * 8, lA + (i * 256 + wid * 64) * 16);
    }
    #pragma unroll
    for (int i = 0; i < 2; ++i) {
      int slot = t + i * 256;
      int row = slot >> 3, sw = (t & 7) ^ (row & 7);
      gload_lds16(Bt + (size_t)(n0 + row) * D_ + k0 + sw * 8, lB + (i * 256 + wid * 64) * 16);
    }
    __syncthreads();
    #pragma unroll
    for (int ks = 0; ks < 2; ++ks) {
      s16x8 af[4], bf[2];
      #pragma unroll
      for (int mt = 0; mt < 4; ++mt) {
        int row = wm * 64 + mt * 16 + l15;
        af[mt] = *reinterpret_cast<const s16x8*>(lA + row * 128 + (((ks*4 + l4) ^ (row & 7)) * 16));
      }
      #pragma unroll
      for (int nt = 0; nt < 2; ++nt) {
        int row = wn * 32 + nt * 16 + l15;
        bf[nt] = *reinterpret_cast<const s16x8*>(lB + row * 128 + (((ks*4 + l4) ^ (row & 7)) * 16));
      }
      #pragma unroll
      for (int mt = 0; mt < 4; ++mt)
        #pragma unroll
        for (int nt = 0; nt < 2; ++nt)
          acc[mt][nt] = __builtin_amdgcn_mfma_f32_16x16x32_bf16(af[mt], bf[nt], acc[mt][nt], 0, 0, 0);
    }
    __syncthreads();
  }
  #pragma unroll
  for (int nt = 0; nt < 2; ++nt) {
    int col = n0 + wn * 32 + nt * 16 + l15;
    float bv = bias[col];
    #pragma unroll
    for (int mt = 0; mt < 4; ++mt) {
      int row0 = m0 + wm * 64 + mt * 16 + l4 * 4;
      #pragma unroll
      for (int r = 0; r < 4; ++r)
        C[(size_t)(row0 + r) * D_ + col] = acc[mt][nt][r] + bv;
    }
  }
}

// ---------------- flash attention, swapped-QK^T, 2-phase dbuf ----------------
// grid (S/64 qblk, B*H); block 256 = 4 waves; wave owns 16 q-rows; KVBLK=64.
// Q pre-scaled by C1_ (softmax in log2 domain). V stored transposed [D][M].
__global__ __launch_bounds__(256, 4) void k_attn(const short* __restrict__ Q,
                                                 const short* __restrict__ K,
                                                 const short* __restrict__ Vt,
                                                 short* __restrict__ O) {
  // [0,16384): K dbuf (2x 64x128B)  [16384,32768): V dbuf  [32768,40960): per-wave P
  __shared__ __align__(16) char lds[40960];
  const int t = threadIdx.x;
  const int lane = t & 63, wid = t >> 6;
  const int l15 = lane & 15, l4 = lane >> 4;
  const int bh = blockIdx.y, b = bh >> 4, h = bh & 15;
  const int q0 = blockIdx.x * 64;
  const size_t qkbase = (size_t)b * S_ * D_ + h * HD_;
  const short* gK = K + qkbase;
  const short* gVt = Vt + (size_t)(h * HD_) * M_ + (size_t)b * S_;

  // Q fragments (B-operand of swapped QK^T): lane holds Q[q=l15][d=ks*32+l4*8+i]
  s16x8 qf[2];
  {
    const short* qp = Q + qkbase + (size_t)(q0 + wid * 16 + l15) * D_;
    qf[0] = *reinterpret_cast<const s16x8*>(qp + l4 * 8);
    qf[1] = *reinterpret_cast<const s16x8*>(qp + 32 + l4 * 8);
  }

  f32x4 o_acc[4];                  // O[q=l4*4+r][d=nt*16+l15]
  #pragma unroll
  for (int nt = 0; nt < 4; ++nt) o_acc[nt] = (f32x4){0.f, 0.f, 0.f, 0.f};
  float m_run = -INFINITY, l_run = 0.f;   // for q = l15

  char* lPw = lds + 32768 + wid * 2048;

  auto stage = [&](int kvt, int bb) {
    const short* gKt  = gK  + (size_t)(kvt * 64) * D_;
    const short* gVtt = gVt + kvt * 64;
    #pragma unroll
    for (int i = 0; i < 2; ++i) {
      int slot = t + i * 256;
      int row = slot >> 3, sw = (t & 7) ^ (row & 7);
      char* dst = lds + bb * 8192 + i * 4096 + wid * 1024;
      gload_lds16(gKt  + (size_t)row * D_ + sw * 8, dst);
      gload_lds16(gVtt + (size_t)row * M_ + sw * 8, dst + 16384);
    }
  };

  stage(0, 0);
  __syncthreads();
  int cur = 0;

  for (int kt0 = 0; kt0 < S_ / 64; ++kt0) {
    if (kt0 < S_ / 64 - 1) stage(kt0 + 1, cur ^ 1);
    const char* bK = lds + cur * 8192;
    const char* bV = lds + 16384 + cur * 8192;

    // S^T = K·Q^T : lane holds S[q=l15][kv=kt*16+l4*4+r] (log2 units)
    f32x4 sc[4];
    #pragma unroll
    for (int kt = 0; kt < 4; ++kt) sc[kt] = (f32x4){0.f, 0.f, 0.f, 0.f};
    __builtin_amdgcn_s_setprio(1);
    #pragma unroll
    for (int ks = 0; ks < 2; ++ks)
      #pragma unroll
      for (int kt = 0; kt < 4; ++kt) {
        int row = kt * 16 + l15;
        s16x8 kf = *reinterpret_cast<const s16x8*>(bK + row * 128 + (((ks*4 + l4) ^ (row & 7)) * 16));
        sc[kt] = __builtin_amdgcn_mfma_f32_16x16x32_bf16(kf, qf[ks], sc[kt], 0, 0, 0);
      }
    __builtin_amdgcn_s_setprio(0);

    // online softmax, defer-max (T13)
    float mx = fmaxf(fmaxf(fmaxf(sc[0][0], sc[0][1]), fmaxf(sc[0][2], sc[0][3])),
                     fmaxf(fmaxf(sc[1][0], sc[1][1]), fmaxf(sc[1][2], sc[1][3])));
    mx = fmaxf(mx, fmaxf(fmaxf(fmaxf(sc[2][0], sc[2][1]), fmaxf(sc[2][2], sc[2][3])),
                         fmaxf(fmaxf(sc[3][0], sc[3][1]), fmaxf(sc[3][2], sc[3][3]))));
    mx = fmaxf(mx, __shfl_xor(mx, 16));
    mx = fmaxf(mx, __shfl_xor(mx, 32));
    if (!__all(mx <= m_run + THR_)) {
      float mnew = fmaxf(m_run, mx);
      float alpha = exp2f(m_run - mnew);
      float ar[4];
      #pragma unroll
      for (int r = 0; r < 4; ++r) ar[r] = __shfl(alpha, l4 * 4 + r);
      #pragma unroll
      for (int nt = 0; nt < 4; ++nt)
        #pragma unroll
        for (int r = 0; r < 4; ++r) o_acc[nt][r] *= ar[r];
      l_run *= alpha;
      m_run = mnew;
    }
    float rs = 0.f;
    unsigned pk[4][2];
    #pragma unroll
    for (int kt = 0; kt < 4; ++kt) {
      float p0 = exp2f(sc[kt][0] - m_run), p1 = exp2f(sc[kt][1] - m_run);
      float p2 = exp2f(sc[kt][2] - m_run), p3 = exp2f(sc[kt][3] - m_run);
      rs += (p0 + p1) + (p2 + p3);
      pk[kt][0] = cvt_pk_bf16(p0, p1);
      pk[kt][1] = cvt_pk_bf16(p2, p3);
    }
    rs += __shfl_xor(rs, 16);
    rs += __shfl_xor(rs, 32);
    l_run += rs;

    // P -> per-wave LDS (A-layout [q=16][kv=64], XOR-swizzled), same-wave so no barrier
    #pragma unroll
    for (int kt = 0; kt < 4; ++kt) {
      unsigned long long w = (unsigned long long)pk[kt][0] | ((unsigned long long)pk[kt][1] << 32);
      *reinterpret_cast<unsigned long long*>(
          lPw + l15 * 128 + ((kt * 32 + l4 * 8) ^ ((l15 & 7) << 4))) = w;
    }

    // PV: A = P[q][kv], B = V[kv][d] from transposed bV rows
    __builtin_amdgcn_s_setprio(1);
    #pragma unroll
    for (int ks = 0; ks < 2; ++ks) {
      s16x8 pf = *reinterpret_cast<const s16x8*>(
          lPw + l15 * 128 + ((ks * 64 + l4 * 16) ^ ((l15 & 7) << 4)));
      #pragma unroll
      for (int nt = 0; nt < 4; ++nt) {
        int row = nt * 16 + l15;
        s16x8 vf = *reinterpret_cast<const s16x8*>(bV + row * 128 + (((ks*4 + l4) ^ (row & 7)) * 16));
        o_acc[nt] = __builtin_amdgcn_mfma_f32_16x16x32_bf16(pf, vf, o_acc[nt], 0, 0, 0);
      }
    }
    __builtin_amdgcn_s_setprio(0);

    __syncthreads();   // next-tile staging landed; this tile's buffers free
    cur ^= 1;
  }

  // epilogue: O /= l, write bf16
  float lr[4];
  #pragma unroll
  for (int r = 0; r < 4; ++r) lr[r] = 1.f / __shfl(l_run, l4 * 4 + r);
  #pragma unroll
  for (int nt = 0; nt < 4; ++nt) {
    int col = nt * 16 + l15;
    #pragma unroll
    for (int r = 0; r < 4; ++r) {
      int row = q0 + wid * 16 + l4 * 4 + r;
      O[qkbase + (size_t)row * D_ + col] = f2bf(o_acc[nt][r] * lr[r]);
    }
  }
}

extern "C" void kernel_launch(void* const* d_in, const int* in_sizes, int n_in,
                              void* d_out, int out_size, void* d_ws, size_t ws_size,
                              hipStream_t stream) {
  const float* query = (const float*)d_in[0];
  const float* Wq = (const float*)d_in[1];
  const float* bq = (const float*)d_in[2];
  const float* Wk = (const float*)d_in[3];
  const float* bk = (const float*)d_in[4];
  const float* Wv = (const float*)d_in[5];
  const float* bv = (const float*)d_in[6];
  const float* Wo = (const float*)d_in[7];
  const float* bo = (const float*)d_in[8];
  float* out = (float*)d_out;

  const size_t NE = (size_t)M_ * D_;
  short* ws   = (short*)d_ws;
  short* xbf  = ws;                            // query bf16
  short* qbf  = ws + NE;                       // Q (pre-scaled by C1_)
  short* kbf  = ws + 2 * NE;
  short* vtbf = ws + 3 * NE;                   // V transposed [D][M]
  short* aout = ws + 4 * NE;                   // attention output bf16
  short* wtq  = ws + 5 * NE;
  short* wtk  = wtq + (size_t)D_ * D_;
  short* wtv  = wtk + (size_t)D_ * D_;
  short* wto  = wtv + (size_t)D_ * D_;

  k_cvt_bf16<<<(int)(NE / (8 * 256)), 256, 0, stream>>>(query, xbf, (int)NE);
  k_transpose4<<<dim3(512, 4), 256, 0, stream>>>(Wq, Wk, Wv, Wo, wtq, wtk, wtv, wto);

  k_gemm_qkv<<<dim3(M_ / 128, D_ / 128, 3), 256, 0, stream>>>(
      xbf, wtq, wtk, wtv, bq, bk, bv, qbf, kbf, vtbf);

  k_attn<<<dim3(S_ / 64, B_ * H_), 256, 0, stream>>>(qbf, kbf, vtbf, aout);

  k_gemm_out<<<dim3(M_ / 128, D_ / 64), 256, 0, stream>>>(aout, wto, bo, out);
}